// Round 1
// baseline (1100.069 us; speedup 1.0000x reference)
//
#include <hip/hip_runtime.h>
#include <math.h>

#define D_MODEL  2048
#define N_HEADS  16
#define HEAD_DIM 128
#define BATCH    16
#define SEQ      4096
#define NCHUNK   8
#define CHUNK    (SEQ / NCHUNK)   // 512

// ---------------------------------------------------------------------------
// wave-wide (64-lane) butterfly sum
// ---------------------------------------------------------------------------
__device__ __forceinline__ float wave_reduce_sum(float v) {
#pragma unroll
    for (int off = 32; off > 0; off >>= 1)
        v += __shfl_xor(v, off, 64);
    return v;
}

// ---------------------------------------------------------------------------
// K1: qkv[w][b][j] = sum_d x[b][d] * W_w[j][d]   (w = 0:q, 1:k, 2:v)
// grid = 3*2048/4 blocks x 256 threads; one wave per (w, j)
// ---------------------------------------------------------------------------
__global__ __launch_bounds__(256) void qkv_gemv(
    const float* __restrict__ x,
    const float* __restrict__ Wq,
    const float* __restrict__ Wk,
    const float* __restrict__ Wv,
    float* __restrict__ qkv) {
    const int wid  = threadIdx.x >> 6;
    const int lane = threadIdx.x & 63;
    const int jg   = blockIdx.x * 4 + wid;   // 0..6143
    const int w    = jg >> 11;               // / 2048
    const int j    = jg & 2047;
    const float* W = (w == 0) ? Wq : (w == 1) ? Wk : Wv;
    const float4* Wrow = (const float4*)(W + (size_t)j * D_MODEL);

    float acc[BATCH];
#pragma unroll
    for (int b = 0; b < BATCH; ++b) acc[b] = 0.f;

#pragma unroll
    for (int it = 0; it < D_MODEL / 256; ++it) {   // 8 iterations
        const float4 w4 = Wrow[it * 64 + lane];
#pragma unroll
        for (int b = 0; b < BATCH; ++b) {
            const float4 x4 = ((const float4*)(x + (size_t)b * D_MODEL))[it * 64 + lane];
            acc[b] = fmaf(w4.x, x4.x, fmaf(w4.y, x4.y, fmaf(w4.z, x4.z, fmaf(w4.w, x4.w, acc[b]))));
        }
    }

    float mine = 0.f;
#pragma unroll
    for (int b = 0; b < BATCH; ++b) {
        const float r = wave_reduce_sum(acc[b]);
        if (lane == b) mine = r;
    }
    if (lane < BATCH)
        qkv[(size_t)w * (BATCH * D_MODEL) + (size_t)lane * D_MODEL + j] = mine;
}

// ---------------------------------------------------------------------------
// K2: flash-decode chunk. grid = 256 pairs * NCHUNK, 256 threads (4 waves).
// One cache row per wave per step; online softmax per wave; LDS merge of the
// 4 waves; per-chunk (m, l, acc[128]) written to stats.
// ---------------------------------------------------------------------------
__global__ __launch_bounds__(256) void attn_chunk(
    const float* __restrict__ cache_k,
    const float* __restrict__ cache_v,
    const float* __restrict__ qkv,
    float* __restrict__ stats) {
    const int wid  = threadIdx.x >> 6;
    const int lane = threadIdx.x & 63;
    const int c    = blockIdx.x & (NCHUNK - 1);
    const int pair = blockIdx.x >> 3;          // b*16 + h
    const int b    = pair >> 4;
    const int h    = pair & 15;
    const float scale = 0.08838834764831845f;  // 128^-0.5

    const float* qptr = qkv + (size_t)b * D_MODEL + h * HEAD_DIM;
    const float q0 = qptr[2 * lane];
    const float q1 = qptr[2 * lane + 1];

    const float* kbase = cache_k + (size_t)pair * SEQ * HEAD_DIM;
    const float* vbase = cache_v + (size_t)pair * SEQ * HEAD_DIM;

    float m = -INFINITY, l = 0.f, a0 = 0.f, a1 = 0.f;
    const int s0 = c * CHUNK;
    for (int s = s0 + wid; s < s0 + CHUNK; s += 4) {
        const float2 k2 = *(const float2*)(kbase + (size_t)s * HEAD_DIM + 2 * lane);
        const float2 v2 = *(const float2*)(vbase + (size_t)s * HEAD_DIM + 2 * lane);
        float part = fmaf(q0, k2.x, q1 * k2.y);
        part = wave_reduce_sum(part);
        const float logit = part * scale;
        const float newm = fmaxf(m, logit);
        const float corr = __expf(m - newm);       // first iter: exp(-inf) = 0
        const float p    = __expf(logit - newm);
        l  = fmaf(l,  corr, p);
        a0 = fmaf(a0, corr, p * v2.x);
        a1 = fmaf(a1, corr, p * v2.y);
        m = newm;
    }

    __shared__ float s_m[4], s_l[4];
    __shared__ float s_acc[4][128];
    s_acc[wid][2 * lane]     = a0;
    s_acc[wid][2 * lane + 1] = a1;
    if (lane == 0) { s_m[wid] = m; s_l[wid] = l; }
    __syncthreads();

    if (threadIdx.x < 128) {
        const int t = threadIdx.x;
        const float M = fmaxf(fmaxf(s_m[0], s_m[1]), fmaxf(s_m[2], s_m[3]));
        float L = 0.f, A = 0.f;
#pragma unroll
        for (int wv = 0; wv < 4; ++wv) {
            const float f = __expf(s_m[wv] - M);
            L += s_l[wv] * f;
            A = fmaf(s_acc[wv][t], f, A);
        }
        float* st = stats + ((size_t)pair * NCHUNK + c) * 130;
        st[2 + t] = A;
        if (t == 0) { st[0] = M; st[1] = L; }
    }
}

// ---------------------------------------------------------------------------
// K3: merge 8 chunk partials + the new token's k/v row; normalize.
// grid = 256 blocks x 64 threads (one wave per (b,h)).
// ---------------------------------------------------------------------------
__global__ __launch_bounds__(64) void attn_combine(
    const float* __restrict__ qkv,
    const float* __restrict__ stats,
    float* __restrict__ attn) {
    const int pair = blockIdx.x;
    const int lane = threadIdx.x;
    const int b = pair >> 4;
    const int h = pair & 15;
    const float scale = 0.08838834764831845f;

    const float* qptr = qkv + (size_t)b * D_MODEL + h * HEAD_DIM;
    const float* kptr = qkv + (size_t)(BATCH * D_MODEL)     + (size_t)b * D_MODEL + h * HEAD_DIM;
    const float* vptr = qkv + (size_t)(2 * BATCH * D_MODEL) + (size_t)b * D_MODEL + h * HEAD_DIM;

    const float q0 = qptr[2 * lane], q1 = qptr[2 * lane + 1];
    const float k0 = kptr[2 * lane], k1 = kptr[2 * lane + 1];
    float part = fmaf(q0, k0, q1 * k1);
    part = wave_reduce_sum(part);
    const float logit = part * scale;

    const float* st = stats + (size_t)pair * NCHUNK * 130;
    float M = logit;
#pragma unroll
    for (int cc = 0; cc < NCHUNK; ++cc) M = fmaxf(M, st[cc * 130]);

    const float pnew = __expf(logit - M);
    float L  = pnew;
    float a0 = pnew * vptr[2 * lane];
    float a1 = pnew * vptr[2 * lane + 1];
#pragma unroll
    for (int cc = 0; cc < NCHUNK; ++cc) {
        const float* s = st + cc * 130;
        const float f = __expf(s[0] - M);
        L += s[1] * f;
        a0 = fmaf(s[2 + 2 * lane],     f, a0);
        a1 = fmaf(s[2 + 2 * lane + 1], f, a1);
    }
    const float inv = 1.f / L;
    float* o = attn + (size_t)b * D_MODEL + h * HEAD_DIM;
    o[2 * lane]     = a0 * inv;
    o[2 * lane + 1] = a1 * inv;
}

// ---------------------------------------------------------------------------
// K4: out[b][j] = sum_d attn[b][d] * Wo[j][d].  One wave per j.
// ---------------------------------------------------------------------------
__global__ __launch_bounds__(256) void out_gemv(
    const float* __restrict__ attn,
    const float* __restrict__ Wo,
    float* __restrict__ out) {
    const int wid  = threadIdx.x >> 6;
    const int lane = threadIdx.x & 63;
    const int j    = blockIdx.x * 4 + wid;   // 0..2047
    const float4* Wrow = (const float4*)(Wo + (size_t)j * D_MODEL);

    float acc[BATCH];
#pragma unroll
    for (int b = 0; b < BATCH; ++b) acc[b] = 0.f;

#pragma unroll
    for (int it = 0; it < D_MODEL / 256; ++it) {
        const float4 w4 = Wrow[it * 64 + lane];
#pragma unroll
        for (int b = 0; b < BATCH; ++b) {
            const float4 x4 = ((const float4*)(attn + (size_t)b * D_MODEL))[it * 64 + lane];
            acc[b] = fmaf(w4.x, x4.x, fmaf(w4.y, x4.y, fmaf(w4.z, x4.z, fmaf(w4.w, x4.w, acc[b]))));
        }
    }

    float mine = 0.f;
#pragma unroll
    for (int b = 0; b < BATCH; ++b) {
        const float r = wave_reduce_sum(acc[b]);
        if (lane == b) mine = r;
    }
    if (lane < BATCH)
        out[(size_t)lane * D_MODEL + j] = mine;
}

// ---------------------------------------------------------------------------
extern "C" void kernel_launch(void* const* d_in, const int* in_sizes, int n_in,
                              void* d_out, int out_size, void* d_ws, size_t ws_size,
                              hipStream_t stream) {
    const float* x  = (const float*)d_in[0];
    const float* ck = (const float*)d_in[1];
    const float* cv = (const float*)d_in[2];
    const float* Wq = (const float*)d_in[3];
    const float* Wk = (const float*)d_in[4];
    const float* Wv = (const float*)d_in[5];
    const float* Wo = (const float*)d_in[6];

    float* ws    = (float*)d_ws;
    float* qkv   = ws;                       // 3*16*2048   = 98304 floats
    float* attn  = ws + 98304;               // 16*2048     = 32768 floats
    float* stats = ws + 98304 + 32768;       // 256*8*130   = 266240 floats

    qkv_gemv   <<<(3 * D_MODEL) / 4, 256, 0, stream>>>(x, Wq, Wk, Wv, qkv);
    attn_chunk <<<256 * NCHUNK,      256, 0, stream>>>(ck, cv, qkv, stats);
    attn_combine<<<256,               64, 0, stream>>>(qkv, stats, attn);
    out_gemv   <<<D_MODEL / 4,       256, 0, stream>>>(attn, Wo, (float*)d_out);
}